// Round 1
// baseline (2109.008 us; speedup 1.0000x reference)
//
#include <hip/hip_runtime.h>

// Problem constants (fixed by the reference setup)
#define IMG_N   8
#define IMG_H   512
#define IMG_W   512
#define BLK     32      // block size
#define NBH     16      // blocks per column (p % 16 -> bh)
#define P_CNT   256
#define PSFN    64
#define OUTK    127     // 2*PSFN - 1
#define SENS    1024

// LDS weight layout: WpT[row = b+8][col = a+1], row stride 66.
//   valid a,b in [-1,63]; rows 0..6 and 72..79 are zero pad (b out of range),
//   col 65 is zero pad (a out of range). Lane-varying index is a (fast axis)
//   -> conflict-free LDS reads.
#define WP_STRIDE 66
#define WP_ROWS   80

__global__ __launch_bounds__(256) void svconv_splat(
    const float* __restrict__ imgs, const float* __restrict__ psf,
    const float* __restrict__ xc, const float* __restrict__ yc,
    float* __restrict__ out)
{
    __shared__ float blk_s[BLK * BLK];
    __shared__ float WpT[WP_ROWS * WP_STRIDE];

    const int bid = blockIdx.x;
    const int n = bid >> 8;
    const int p = bid & 255;
    const int bh = p & 15;      // pairs with i / X axis
    const int bw = p >> 4;      // pairs with j / Y axis
    const int tid = threadIdx.x;

    // ---- zero LDS weight array (incl. all pads) ----
    for (int idx = tid; idx < WP_ROWS * WP_STRIDE; idx += 256) WpT[idx] = 0.0f;

    // ---- load 32x32 image block ----
    const float* src = imgs + ((size_t)n * IMG_H + bh * BLK) * IMG_W + bw * BLK;
    for (int idx = tid; idx < BLK * BLK; idx += 256) {
        int r = idx >> 5, c = idx & 31;
        blk_s[idx] = src[r * IMG_W + c];
    }
    __syncthreads();   // zero-phase must complete before fill

    // ---- build Wp (2x2 aggregated PSF), transposed into LDS ----
    const float* psfp = psf + (size_t)p * PSFN * PSFN;
    for (int idx = tid; idx < 65 * 65; idx += 256) {
        int ai = idx % 65;          // = a+1, a in [-1,63]
        int bi = idx / 65;          // = b+1, b in [-1,63]
        int a = ai - 1, b = bi - 1;
        float s = 0.0f;
        #pragma unroll
        for (int du = 0; du < 2; ++du) {
            #pragma unroll
            for (int dv = 0; dv < 2; ++dv) {
                int x = a + du, y = b + dv;
                if ((unsigned)x < 64u && (unsigned)y < 64u)
                    s += psfp[x * PSFN + y];
            }
        }
        WpT[(b + 8) * WP_STRIDE + ai] = s;
    }
    __syncthreads();

    const int wave = tid >> 6;
    const int lane = tid & 63;
    const int icen = 512 + __float2int_rn(xc[p] * 1e6f);
    const int jcen = 512 + __float2int_rn(yc[p] * 1e6f);

    // work unit u: jt = u>>1 (16 j-tiles of 8), ib = u&1 (i = ib*64 + lane)
    for (int u = wave; u < 32; u += 4) {
        const int jt = u >> 1;
        const int j0 = jt << 3;
        const int i  = ((u & 1) << 6) | lane;
        const int jmaxv = (j0 + 7 < 126) ? (j0 + 7) : 126;
        int cmin = (j0 - 63) >> 1; if (cmin < 0) cmin = 0;
        int cmax = jmaxv >> 1;     if (cmax > 31) cmax = 31;

        float acc[8] = {0.f,0.f,0.f,0.f,0.f,0.f,0.f,0.f};

        for (int r = 0; r < 32; ++r) {
            int a = 2 * r + 63 - i;                       // lane-varying row offset
            int acol = ((unsigned)(a + 1) <= 64u) ? (a + 1) : 65;  // 65 = zero pad col
            const float* q = &WpT[(2 * cmin - j0 + 64) * WP_STRIDE + acol];
            float wv0 = q[0*WP_STRIDE], wv1 = q[1*WP_STRIDE];
            float wv2 = q[2*WP_STRIDE], wv3 = q[3*WP_STRIDE];
            float wv4 = q[4*WP_STRIDE], wv5 = q[5*WP_STRIDE];
            float wv6 = q[6*WP_STRIDE], wv7 = q[7*WP_STRIDE];
            const float* brow = &blk_s[r * 32];
            int c = cmin;
            while (true) {
                float bv = brow[c];                       // wave-uniform broadcast
                acc[0] = fmaf(bv, wv7, acc[0]);
                acc[1] = fmaf(bv, wv6, acc[1]);
                acc[2] = fmaf(bv, wv5, acc[2]);
                acc[3] = fmaf(bv, wv4, acc[3]);
                acc[4] = fmaf(bv, wv3, acc[4]);
                acc[5] = fmaf(bv, wv2, acc[5]);
                acc[6] = fmaf(bv, wv1, acc[6]);
                acc[7] = fmaf(bv, wv0, acc[7]);
                if (++c > cmax) break;
                q += 2 * WP_STRIDE;                       // window slides by 2 rows
                wv0 = wv2; wv1 = wv3; wv2 = wv4; wv3 = wv5; wv4 = wv6; wv5 = wv7;
                wv6 = q[6*WP_STRIDE];
                wv7 = q[7*WP_STRIDE];
            }
        }

        // ---- splat into sensor ----
        if (i <= 126) {
            int sx = icen - 63 + i;
            if ((unsigned)sx < (unsigned)SENS) {
                float* orow = out + ((size_t)n << 20) + (size_t)sx * SENS;
                #pragma unroll
                for (int t = 0; t < 8; ++t) {
                    int j = j0 + t;
                    int sy = jcen - 63 + j;
                    if (j <= 126 && (unsigned)sy < (unsigned)SENS)
                        atomicAdd(&orow[sy], acc[t]);
                }
            }
        }
    }
}

extern "C" void kernel_launch(void* const* d_in, const int* in_sizes, int n_in,
                              void* d_out, int out_size, void* d_ws, size_t ws_size,
                              hipStream_t stream) {
    const float* imgs = (const float*)d_in[0];
    const float* psf  = (const float*)d_in[1];
    // d_in[2], d_in[3] are the X/Y meshgrids — only their shape matters (1024x1024)
    const float* xc   = (const float*)d_in[4];
    const float* yc   = (const float*)d_in[5];
    float* out = (float*)d_out;

    hipMemsetAsync(out, 0, (size_t)out_size * sizeof(float), stream);
    svconv_splat<<<dim3(IMG_N * P_CNT), dim3(256), 0, stream>>>(imgs, psf, xc, yc, out);
}

// Round 2
// 1834.652 us; speedup vs baseline: 1.1495x; 1.1495x over previous
//
#include <hip/hip_runtime.h>

#define IMG_N   8
#define IMG_H   512
#define IMG_W   512
#define BLK     32
#define P_CNT   256
#define PSFN    64
#define SENS    1024

// Paired-row weight layout: for b in [-8, 71] (row = b+8 in [0,79]),
// pair = row>>1 (0..39), parity = row&1, acol = a+1 (0..64; col 65 pad).
// Element index = pair*132 + acol*2 + parity.  Rows 0..6 and 72..79 are zero
// pad (b outside [-1,63]); col usage: acol 0 = a=-1 (ghost phase), 1..64 main.
#define WPAIRS   40
#define WPSTRIDE 132   // floats per pair (66 cols * 2 parities)

__global__ __launch_bounds__(256) void svconv_splat(
    const float* __restrict__ imgs, const float* __restrict__ psf,
    const float* __restrict__ xc, const float* __restrict__ yc,
    float* __restrict__ out)
{
    __shared__ float WpT2[WPAIRS * WPSTRIDE];   // 21120 B
    __shared__ float blk_s[BLK * BLK];          //  4096 B

    const int bid = blockIdx.x;
    const int n = bid >> 8;
    const int p = bid & 255;
    const int bh = p & 15;      // pairs with i / X axis
    const int bw = p >> 4;      // pairs with j / Y axis
    const int tid = threadIdx.x;

    // ---- zero weight LDS (covers all pads) ----
    for (int idx = tid; idx < WPAIRS * WPSTRIDE; idx += 256) WpT2[idx] = 0.0f;

    // ---- load 32x32 image block ----
    const float* src = imgs + ((size_t)n * IMG_H + bh * BLK) * IMG_W + bw * BLK;
    for (int idx = tid; idx < BLK * BLK; idx += 256) {
        int r = idx >> 5, c = idx & 31;
        blk_s[idx] = src[r * IMG_W + c];
    }
    __syncthreads();

    // ---- build Wp (2x2 aggregated PSF) into paired layout ----
    const float* psfp = psf + (size_t)p * PSFN * PSFN;
    for (int idx = tid; idx < 65 * 65; idx += 256) {
        int ai = idx % 65;          // acol = a+1, a in [-1,63]
        int bi = idx / 65;          // b+1, b in [-1,63]
        int a = ai - 1, b = bi - 1;
        float s = 0.0f;
        #pragma unroll
        for (int du = 0; du < 2; ++du)
            #pragma unroll
            for (int dv = 0; dv < 2; ++dv) {
                int x = a + du, y = b + dv;
                if ((unsigned)x < 64u && (unsigned)y < 64u)
                    s += psfp[x * PSFN + y];
            }
        int row = b + 8;
        WpT2[(row >> 1) * WPSTRIDE + ai * 2 + (row & 1)] = s;
    }
    __syncthreads();

    const int wv = tid >> 6;
    const int lane = tid & 63;
    const int icen = 512 + __float2int_rn(xc[p] * 1e6f);
    const int jcen = 512 + __float2int_rn(yc[p] * 1e6f);
    float* const outn = out + ((size_t)n << 20);

    // ================= main systolic phase =================
    // lane <-> fixed a = 63 - lane (acol = 64 - lane).  At r-step r, lane l
    // accumulates output i = 2r + l.  Accs shift down 2 lanes per r-step.
    const int acol = 64 - lane;

    for (int jt = wv; jt < 16; jt += 4) {
        const int j0 = jt << 3;
        int cmin = (j0 - 63) >> 1; if (cmin < 0) cmin = 0;
        int cmax = (j0 + 7) >> 1;  if (cmax > 31) cmax = 31;
        const int ns4 = (cmax - cmin + 1) >> 2;       // trip counts are x4
        const int pair0 = cmin - (j0 >> 1) + 32;      // row0/2, row0 even
        const int sy0 = jcen - 63 + j0;

        float acc[8] = {0.f,0.f,0.f,0.f,0.f,0.f,0.f,0.f};
        const float2* const qbase =
            (const float2*)&WpT2[pair0 * WPSTRIDE + acol * 2];

        for (int r = 0; r < 32; ++r) {
            // init 4-pair register window (pairs pair0 .. pair0+3)
            float2 P0 = qbase[0 * 66];
            float2 P1 = qbase[1 * 66];
            float2 P2 = qbase[2 * 66];
            float2 P3 = qbase[3 * 66];
            const float* brow = &blk_s[r * 32 + cmin];
            const float2* q2 = qbase + 4 * 66;

            for (int s4 = 0; s4 < ns4; ++s4) {
                const float4 bv4 = *(const float4*)(brow + 4 * s4);
                // ---- k = 0 (slots: P[k..k+3] = P0..P3) ----
                {
                    const float bv = bv4.x;
                    acc[0] = fmaf(bv, P3.y, acc[0]);
                    acc[1] = fmaf(bv, P3.x, acc[1]);
                    acc[2] = fmaf(bv, P2.y, acc[2]);
                    acc[3] = fmaf(bv, P2.x, acc[3]);
                    acc[4] = fmaf(bv, P1.y, acc[4]);
                    acc[5] = fmaf(bv, P1.x, acc[5]);
                    acc[6] = fmaf(bv, P0.y, acc[6]);
                    acc[7] = fmaf(bv, P0.x, acc[7]);
                    P0 = q2[0 * 66];
                }
                // ---- k = 1 ----
                {
                    const float bv = bv4.y;
                    acc[0] = fmaf(bv, P0.y, acc[0]);
                    acc[1] = fmaf(bv, P0.x, acc[1]);
                    acc[2] = fmaf(bv, P3.y, acc[2]);
                    acc[3] = fmaf(bv, P3.x, acc[3]);
                    acc[4] = fmaf(bv, P2.y, acc[4]);
                    acc[5] = fmaf(bv, P2.x, acc[5]);
                    acc[6] = fmaf(bv, P1.y, acc[6]);
                    acc[7] = fmaf(bv, P1.x, acc[7]);
                    P1 = q2[1 * 66];
                }
                // ---- k = 2 ----
                {
                    const float bv = bv4.z;
                    acc[0] = fmaf(bv, P1.y, acc[0]);
                    acc[1] = fmaf(bv, P1.x, acc[1]);
                    acc[2] = fmaf(bv, P0.y, acc[2]);
                    acc[3] = fmaf(bv, P0.x, acc[3]);
                    acc[4] = fmaf(bv, P3.y, acc[4]);
                    acc[5] = fmaf(bv, P3.x, acc[5]);
                    acc[6] = fmaf(bv, P2.y, acc[6]);
                    acc[7] = fmaf(bv, P2.x, acc[7]);
                    P2 = q2[2 * 66];
                }
                // ---- k = 3 ----
                {
                    const float bv = bv4.w;
                    acc[0] = fmaf(bv, P2.y, acc[0]);
                    acc[1] = fmaf(bv, P2.x, acc[1]);
                    acc[2] = fmaf(bv, P1.y, acc[2]);
                    acc[3] = fmaf(bv, P1.x, acc[3]);
                    acc[4] = fmaf(bv, P0.y, acc[4]);
                    acc[5] = fmaf(bv, P0.x, acc[5]);
                    acc[6] = fmaf(bv, P3.y, acc[6]);
                    acc[7] = fmaf(bv, P3.x, acc[7]);
                    P3 = q2[3 * 66];
                }
                q2 += 4 * 66;
            }

            // ---- retire completed outputs i = 2r, 2r+1 (lanes 0,1) ----
            if (lane < 2) {
                const int sx = icen - 63 + 2 * r + lane;
                float* orow = outn + (size_t)sx * SENS + sy0;
                #pragma unroll
                for (int t = 0; t < 8; ++t) atomicAdd(&orow[t], acc[t]);
            }
            // ---- shift accs down 2 lanes; inject zeros at 62,63 ----
            if (r < 31) {
                #pragma unroll
                for (int t = 0; t < 8; ++t) {
                    float v = __shfl_down(acc[t], 2, 64);
                    acc[t] = (lane >= 62) ? 0.0f : v;
                }
            }
        }
        // ---- flush in-flight outputs i = 62+lane (lanes 2..63) ----
        if (lane >= 2) {
            const int sx = icen - 63 + 62 + lane;   // i in [64,125]
            float* orow = outn + (size_t)sx * SENS + sy0;
            #pragma unroll
            for (int t = 0; t < 8; ++t) atomicAdd(&orow[t], acc[t]);
        }
    }

    // ================= ghost phase: a = -1 (acol 0) =================
    // contributes to even outputs i = 2r + 64 (incl. i=126 which gets ONLY this)
    for (int g = wv; g < 64; g += 4) {
        const int r = g >> 1, jb = g & 1;
        const int j = jb * 64 + lane;
        const float* brow = &blk_s[r * 32];
        float gacc = 0.0f;
        #pragma unroll 4
        for (int c = 0; c < 32; ++c) {
            int row = 2 * c - j + 71;               // b + 8
            row = (row < 0) ? 0 : ((row > 72) ? 72 : row);  // clamped rows are 0
            const float w = WpT2[(row >> 1) * WPSTRIDE + (row & 1)];
            gacc = fmaf(brow[c], w, gacc);
        }
        const int sx = icen + 1 + 2 * r;            // i = 2r+64
        const int sy = jcen - 63 + j;
        atomicAdd(outn + (size_t)sx * SENS + sy, gacc);
    }
}

extern "C" void kernel_launch(void* const* d_in, const int* in_sizes, int n_in,
                              void* d_out, int out_size, void* d_ws, size_t ws_size,
                              hipStream_t stream) {
    const float* imgs = (const float*)d_in[0];
    const float* psf  = (const float*)d_in[1];
    const float* xc   = (const float*)d_in[4];
    const float* yc   = (const float*)d_in[5];
    float* out = (float*)d_out;

    hipMemsetAsync(out, 0, (size_t)out_size * sizeof(float), stream);
    svconv_splat<<<dim3(IMG_N * P_CNT), dim3(256), 0, stream>>>(imgs, psf, xc, yc, out);
}

// Round 3
// 1813.625 us; speedup vs baseline: 1.1629x; 1.0116x over previous
//
#include <hip/hip_runtime.h>

#define IMG_N   8
#define IMG_H   512
#define IMG_W   512
#define BLK     32
#define P_CNT   256
#define PSFN    64
#define SENS    1024

// Paired-row weight layout: for b in [-8, 71] (row = b+8 in [0,79]),
// pair = row>>1 (0..39), parity = row&1, acol = a+1 (0..64; col 65 pad).
// Element index = pair*132 + acol*2 + parity.  Rows 0..6 and 72..79 zero pad.
#define WPAIRS   40
#define WPSTRIDE 132   // floats per pair (66 cols * 2 parities)

// Systolic main phase: lane l holds fixed PSF column a = 63 - lane
// (acol = 64 - lane, always valid -> no zero-pad FMA waste). At r-step r,
// lane l accumulates output i = 2r + l; accs shift down 2 lanes per r-step;
// lanes 0,1 retire i = 2r, 2r+1 each step.
//
// Weight indexing (verified vs R2): c = CMIN + m, output j = J0 + t:
//   row = 2c - j + 71 ; with W[q] = pair (PAIR0 + q), PAIR0 = CMIN - J0/2 + 32:
//   acc[t] uses W[m + 3 - (t>>1)], parity .y for even t, .x for odd t.
// The whole window (M+3 pairs, M = #c-steps <= 32) is r-invariant ->
// preloaded to registers ONCE per tile (this round's change).

template<int JT>
__device__ __forceinline__ void tile_compute(
    const float* __restrict__ WpT2, const float* __restrict__ blk_s,
    const int lane, const int icen, const int jcen, float* __restrict__ outn)
{
    constexpr int J0    = JT * 8;
    constexpr int CMIN_ = (J0 - 63) >> 1;
    constexpr int CMIN  = CMIN_ < 0 ? 0 : CMIN_;
    constexpr int CMAX_ = (J0 + 7) >> 1;
    constexpr int CMAX  = CMAX_ > 31 ? 31 : CMAX_;
    constexpr int M     = CMAX - CMIN + 1;          // 4,8,...,32 (multiple of 4)
    constexpr int NP    = M + 3;                    // float2 pairs in window
    constexpr int PAIR0 = CMIN - (J0 >> 1) + 32;

    const int acol = 64 - lane;                     // 1..64, always valid
    const float2* qbase = (const float2*)&WpT2[PAIR0 * WPSTRIDE + acol * 2];

    float2 W[NP];
    #pragma unroll
    for (int q = 0; q < NP; ++q) W[q] = qbase[q * (WPSTRIDE / 2)];

    const int sy0 = jcen - 63 + J0;
    float acc[8] = {0.f,0.f,0.f,0.f,0.f,0.f,0.f,0.f};

    for (int r = 0; r < 32; ++r) {
        const float* brow = &blk_s[r * 32 + CMIN];
        // chunk m-range by 16 to bound register pressure
        #pragma unroll
        for (int m0 = 0; m0 < M; m0 += 16) {
            const int CH = (M - m0 < 16) ? (M - m0) : 16;   // folds per unrolled m0
            float bv[16];
            #pragma unroll
            for (int s = 0; s < 16; s += 4) {
                if (s < CH) {
                    const float4 v = *(const float4*)&brow[m0 + s];
                    bv[s+0] = v.x; bv[s+1] = v.y; bv[s+2] = v.z; bv[s+3] = v.w;
                }
            }
            #pragma unroll
            for (int mm = 0; mm < 16; ++mm) {
                if (mm < CH) {
                    const int m = m0 + mm;
                    const float b = bv[mm];
                    acc[0] = fmaf(b, W[m + 3].y, acc[0]);
                    acc[1] = fmaf(b, W[m + 3].x, acc[1]);
                    acc[2] = fmaf(b, W[m + 2].y, acc[2]);
                    acc[3] = fmaf(b, W[m + 2].x, acc[3]);
                    acc[4] = fmaf(b, W[m + 1].y, acc[4]);
                    acc[5] = fmaf(b, W[m + 1].x, acc[5]);
                    acc[6] = fmaf(b, W[m + 0].y, acc[6]);
                    acc[7] = fmaf(b, W[m + 0].x, acc[7]);
                }
            }
        }

        // retire completed outputs i = 2r, 2r+1 (lanes 0,1)
        if (lane < 2) {
            const int sx = icen - 63 + 2 * r + lane;
            float* orow = outn + (size_t)sx * SENS + sy0;
            #pragma unroll
            for (int t = 0; t < 8; ++t) atomicAdd(&orow[t], acc[t]);
        }
        // shift accs down 2 lanes; inject zeros at lanes 62,63
        if (r < 31) {
            #pragma unroll
            for (int t = 0; t < 8; ++t) {
                float v = __shfl_down(acc[t], 2, 64);
                acc[t] = (lane >= 62) ? 0.0f : v;
            }
        }
    }
    // flush in-flight outputs i = 62 + lane (lanes 2..63 -> i in [64,125])
    if (lane >= 2) {
        const int sx = icen - 63 + 62 + lane;
        float* orow = outn + (size_t)sx * SENS + sy0;
        #pragma unroll
        for (int t = 0; t < 8; ++t) atomicAdd(&orow[t], acc[t]);
    }
}

__global__ __launch_bounds__(256, 4) void svconv_splat(
    const float* __restrict__ imgs, const float* __restrict__ psf,
    const float* __restrict__ xc, const float* __restrict__ yc,
    float* __restrict__ out)
{
    __shared__ float WpT2[WPAIRS * WPSTRIDE];   // 21120 B
    __shared__ float blk_s[BLK * BLK];          //  4096 B

    const int bid = blockIdx.x;
    const int n = bid >> 8;
    const int p = bid & 255;
    const int bh = p & 15;      // pairs with i / X axis
    const int bw = p >> 4;      // pairs with j / Y axis
    const int tid = threadIdx.x;

    // ---- zero weight LDS (covers all pads) ----
    for (int idx = tid; idx < WPAIRS * WPSTRIDE; idx += 256) WpT2[idx] = 0.0f;

    // ---- load 32x32 image block ----
    const float* src = imgs + ((size_t)n * IMG_H + bh * BLK) * IMG_W + bw * BLK;
    for (int idx = tid; idx < BLK * BLK; idx += 256) {
        int r = idx >> 5, c = idx & 31;
        blk_s[idx] = src[r * IMG_W + c];
    }
    __syncthreads();

    // ---- build Wp (2x2 aggregated PSF) into paired layout ----
    const float* psfp = psf + (size_t)p * PSFN * PSFN;
    for (int idx = tid; idx < 65 * 65; idx += 256) {
        int ai = idx % 65;          // acol = a+1, a in [-1,63]
        int bi = idx / 65;          // b+1, b in [-1,63]
        int a = ai - 1, b = bi - 1;
        float s = 0.0f;
        #pragma unroll
        for (int du = 0; du < 2; ++du)
            #pragma unroll
            for (int dv = 0; dv < 2; ++dv) {
                int x = a + du, y = b + dv;
                if ((unsigned)x < 64u && (unsigned)y < 64u)
                    s += psfp[x * PSFN + y];
            }
        int row = b + 8;
        WpT2[(row >> 1) * WPSTRIDE + ai * 2 + (row & 1)] = s;
    }
    __syncthreads();

    const int wv = tid >> 6;
    const int lane = tid & 63;
    const int icen = 512 + __float2int_rn(xc[p] * 1e6f);
    const int jcen = 512 + __float2int_rn(yc[p] * 1e6f);
    float* const outn = out + ((size_t)n << 20);

    // per-wave tiles wv+{0,4,8,12}: Sum(M) = 72 for every wave (balanced)
    switch (wv) {
    case 0:
        tile_compute< 0>(WpT2, blk_s, lane, icen, jcen, outn);
        tile_compute< 4>(WpT2, blk_s, lane, icen, jcen, outn);
        tile_compute< 8>(WpT2, blk_s, lane, icen, jcen, outn);
        tile_compute<12>(WpT2, blk_s, lane, icen, jcen, outn);
        break;
    case 1:
        tile_compute< 1>(WpT2, blk_s, lane, icen, jcen, outn);
        tile_compute< 5>(WpT2, blk_s, lane, icen, jcen, outn);
        tile_compute< 9>(WpT2, blk_s, lane, icen, jcen, outn);
        tile_compute<13>(WpT2, blk_s, lane, icen, jcen, outn);
        break;
    case 2:
        tile_compute< 2>(WpT2, blk_s, lane, icen, jcen, outn);
        tile_compute< 6>(WpT2, blk_s, lane, icen, jcen, outn);
        tile_compute<10>(WpT2, blk_s, lane, icen, jcen, outn);
        tile_compute<14>(WpT2, blk_s, lane, icen, jcen, outn);
        break;
    default:
        tile_compute< 3>(WpT2, blk_s, lane, icen, jcen, outn);
        tile_compute< 7>(WpT2, blk_s, lane, icen, jcen, outn);
        tile_compute<11>(WpT2, blk_s, lane, icen, jcen, outn);
        tile_compute<15>(WpT2, blk_s, lane, icen, jcen, outn);
        break;
    }

    // ================= ghost phase: a = -1 (acol 0) =================
    // contributes to even outputs i = 2r + 64 (incl. i=126 which gets ONLY this)
    for (int g = wv; g < 64; g += 4) {
        const int r = g >> 1, jb = g & 1;
        const int j = jb * 64 + lane;
        const float* brow = &blk_s[r * 32];
        float gacc = 0.0f;
        #pragma unroll 4
        for (int c = 0; c < 32; ++c) {
            int row = 2 * c - j + 71;               // b + 8
            row = (row < 0) ? 0 : ((row > 72) ? 72 : row);  // clamped rows are 0
            const float w = WpT2[(row >> 1) * WPSTRIDE + (row & 1)];
            gacc = fmaf(brow[c], w, gacc);
        }
        const int sx = icen + 1 + 2 * r;            // i = 2r+64
        const int sy = jcen - 63 + j;
        atomicAdd(outn + (size_t)sx * SENS + sy, gacc);
    }
}

extern "C" void kernel_launch(void* const* d_in, const int* in_sizes, int n_in,
                              void* d_out, int out_size, void* d_ws, size_t ws_size,
                              hipStream_t stream) {
    const float* imgs = (const float*)d_in[0];
    const float* psf  = (const float*)d_in[1];
    const float* xc   = (const float*)d_in[4];
    const float* yc   = (const float*)d_in[5];
    float* out = (float*)d_out;

    hipMemsetAsync(out, 0, (size_t)out_size * sizeof(float), stream);
    svconv_splat<<<dim3(IMG_N * P_CNT), dim3(256), 0, stream>>>(imgs, psf, xc, yc, out);
}